// Round 7
// baseline (966.293 us; speedup 1.0000x reference)
//
#include <hip/hip_runtime.h>

#define N_RES 768
#define S_MSA 512
#define TF_D 21
#define MSA_D 49
#define CZ 128
#define CM 256

typedef float v4f __attribute__((ext_vector_type(4)));

// ---------------------------------------------------------------------------
// k_embed: three tiny matmuls from target_feat [N,21]:
//   tfi[n][c] = sum_k tf[n][k] w_i[k][c] + b_i[c] + b_rel[c]   (c<128)
//   tfj[n][c] = sum_k tf[n][k] w_j[k][c] + b_j[c]              (c<128)
//   tfm[n][c] = sum_k tf[n][k] w_m[k][c] + b_m[c] + b_msa[c]   (c<256)
// One block per residue n, 512 threads. Biases folded here so downstream
// kernels are pure adds. ~3 us, not worth touching.
// ---------------------------------------------------------------------------
__global__ __launch_bounds__(512) void k_embed(
    const float* __restrict__ tf,
    const float* __restrict__ w_i, const float* __restrict__ b_i,
    const float* __restrict__ w_j, const float* __restrict__ b_j,
    const float* __restrict__ w_m, const float* __restrict__ b_m,
    const float* __restrict__ b_rel, const float* __restrict__ b_msa,
    float* __restrict__ tfi, float* __restrict__ tfj, float* __restrict__ tfm)
{
    const int n = blockIdx.x;
    const int t = threadIdx.x;
    float a[TF_D];
#pragma unroll
    for (int k = 0; k < TF_D; ++k) a[k] = tf[n * TF_D + k];  // uniform -> s_load

    if (t < CZ) {
        const int c = t;
        float acc = b_i[c] + b_rel[c];
#pragma unroll
        for (int k = 0; k < TF_D; ++k) acc = fmaf(a[k], w_i[k * CZ + c], acc);
        tfi[n * CZ + c] = acc;
    } else if (t < 2 * CZ) {
        const int c = t - CZ;
        float acc = b_j[c];
#pragma unroll
        for (int k = 0; k < TF_D; ++k) acc = fmaf(a[k], w_j[k * CZ + c], acc);
        tfj[n * CZ + c] = acc;
    } else {
        const int c = t - 2 * CZ;
        float acc = b_m[c] + b_msa[c];
#pragma unroll
        for (int k = 0; k < TF_D; ++k) acc = fmaf(a[k], w_m[k * CM + c], acc);
        tfm[n * CM + c] = acc;
    }
}

// ---------------------------------------------------------------------------
// k_msa: out[row][c] = sum_k msa[row][k] * w[k][c] + tfm[row % N][c]
// (both biases folded into tfm).
// v2 changes vs 1032us kernel:
//  - block b owns the CONTIGUOUS row chunk [48b, 48b+48) (was stride-8192
//    grid-stride): msa reads stream 9.4 KB/block sequentially, stores write
//    48 KB/block contiguously, and row % 768 collapses to 48*(b&15)+r.
//  - 4-way split accumulator: dependent-FMA chain latency (~4cy x 49) was
//    capping VALU issue; 4 independent ~12-deep chains are issue-bound.
//  - nontemporal store: 402 MB write-once, keep it out of L2.
// Thread c holds w[:, c] in 49 VGPRs; per-row activation reads are
// wave-uniform (scalarizable -> s_load).
// ---------------------------------------------------------------------------
__global__ __launch_bounds__(256) void k_msa(
    const float* __restrict__ msa,
    const float* __restrict__ w,
    const float* __restrict__ tfm,
    float* __restrict__ out)
{
    const int c = threadIdx.x;
    const int b = blockIdx.x;          // 8192 blocks x 48 rows = 393216 rows
    const int row0 = b * 48;
    const int n0 = (b & 15) * 48;      // == row0 % N_RES  (768 = 16*48)

    float wr[MSA_D];
#pragma unroll
    for (int k = 0; k < MSA_D; ++k) wr[k] = w[k * CM + c];

    const float* __restrict__ ar = msa + (size_t)row0 * MSA_D;
    float* __restrict__ op = out + (size_t)row0 * CM + c;
    const float* __restrict__ tp = tfm + n0 * CM + c;

    for (int r = 0; r < 48; ++r) {
        float av[MSA_D];
#pragma unroll
        for (int k = 0; k < MSA_D; ++k) av[k] = ar[k];  // uniform -> s_load
        ar += MSA_D;

        float a0 = tp[r * CM];  // L2-resident (512 blocks reuse each tfm row)
        float a1 = 0.f, a2 = 0.f, a3 = 0.f;
#pragma unroll
        for (int k = 0; k < 48; k += 4) {
            a0 = fmaf(av[k + 0], wr[k + 0], a0);
            a1 = fmaf(av[k + 1], wr[k + 1], a1);
            a2 = fmaf(av[k + 2], wr[k + 2], a2);
            a3 = fmaf(av[k + 3], wr[k + 3], a3);
        }
        a0 = fmaf(av[48], wr[48], a0);
        const float acc = (a0 + a1) + (a2 + a3);
        __builtin_nontemporal_store(acc, op);
        op += CM;
    }
}

// ---------------------------------------------------------------------------
// k_pair: pair_emb[i][j][c] =
//   w_rel[pos(i,j)][c] + ent(i,j)*w_rel[66][c] + w_rel[67+chain(i,j)][c]
//   + tfi[i][c] + tfj[j][c]
// (b_relpos folded into tfi). The one-hot argmin over integer offsets is the
// identity, so the relpos "matmul" collapses to 3 gathers.
// v2 changes: grid is (96, 768) so i = blockIdx.y is uniform (i-side int
// loads scalarize, the p/768 magic-division is gone) and consecutive bx
// blocks write adjacent 4 KB spans. Nontemporal 16B store via native clang
// vector (HIP float4 is a class type the builtin rejects).
// ---------------------------------------------------------------------------
__global__ __launch_bounds__(256) void k_pair(
    const int* __restrict__ res, const int* __restrict__ sym,
    const int* __restrict__ asym, const int* __restrict__ ent,
    const float* __restrict__ w_rel,
    const float* __restrict__ tfi, const float* __restrict__ tfj,
    float* __restrict__ out)
{
    const int i    = blockIdx.y;         // uniform across block
    const int sub  = threadIdx.x >> 5;   // which j within block, 0..7
    const int lane = threadIdx.x & 31;   // float4 index within row, 0..31
    const int j    = blockIdx.x * 8 + sub;

    const int ri = res[i];               // uniform -> scalar loads
    const int ai = asym[i];
    const int si = sym[i];
    const int ei = ent[i];

    int off = ri - res[j] + 32;
    off = min(max(off, 0), 64);
    const int pos = (ai == asym[j]) ? off : 65;

    const int entv = ei - sym[j];
    int cc = si - sym[j] + 2;
    cc = min(max(cc, 0), 4);
    const int chain = (entv != 0) ? cc : 5;
    const float entf = (float)entv;

    const int c = lane * 4;
    const v4f wp = *(const v4f*)(w_rel + pos * CZ + c);
    const v4f we = *(const v4f*)(w_rel + 66 * CZ + c);
    const v4f wc = *(const v4f*)(w_rel + (67 + chain) * CZ + c);
    const v4f ti = *(const v4f*)(tfi + i * CZ + c);
    const v4f tj = *(const v4f*)(tfj + j * CZ + c);

    const v4f o = wp + entf * we + wc + ti + tj;

    v4f* dst = (v4f*)(out + ((size_t)i * N_RES + j) * CZ + c);
    __builtin_nontemporal_store(o, dst);
}

// ---------------------------------------------------------------------------
extern "C" void kernel_launch(void* const* d_in, const int* in_sizes, int n_in,
                              void* d_out, int out_size, void* d_ws, size_t ws_size,
                              hipStream_t stream) {
    const float* target = (const float*)d_in[0];
    const float* msa    = (const float*)d_in[1];
    const int*   res    = (const int*)d_in[2];
    const int*   sym    = (const int*)d_in[3];
    const int*   asym   = (const int*)d_in[4];
    const int*   ent    = (const int*)d_in[5];
    const float* w_i    = (const float*)d_in[6];
    const float* b_i    = (const float*)d_in[7];
    const float* w_j    = (const float*)d_in[8];
    const float* b_j    = (const float*)d_in[9];
    const float* w_m    = (const float*)d_in[10];
    const float* b_m    = (const float*)d_in[11];
    const float* w_msa  = (const float*)d_in[12];
    const float* b_msa  = (const float*)d_in[13];
    const float* w_rel  = (const float*)d_in[14];
    const float* b_rel  = (const float*)d_in[15];

    float* out_msa  = (float*)d_out;                              // [S,N,CM]
    float* out_pair = out_msa + (size_t)S_MSA * N_RES * CM;       // [N,N,CZ]

    float* tfi = (float*)d_ws;          // [N,CZ]  (+b_i +b_rel)
    float* tfj = tfi + N_RES * CZ;      // [N,CZ]  (+b_j)
    float* tfm = tfj + N_RES * CZ;      // [N,CM]  (+b_m +b_msa)

    hipLaunchKernelGGL(k_embed, dim3(N_RES), dim3(512), 0, stream,
                       target, w_i, b_i, w_j, b_j, w_m, b_m, b_rel, b_msa,
                       tfi, tfj, tfm);
    hipLaunchKernelGGL(k_msa, dim3(8192), dim3(256), 0, stream,
                       msa, w_msa, tfm, out_msa);
    hipLaunchKernelGGL(k_pair, dim3(N_RES / 8, N_RES), dim3(256), 0, stream,
                       res, sym, asym, ent, w_rel, tfi, tfj, out_pair);
}